// Round 4
// baseline (301.939 us; speedup 1.0000x reference)
//
#include <hip/hip_runtime.h>
#include <hip/hip_bf16.h>

typedef __attribute__((ext_vector_type(8))) short short8;
typedef __attribute__((ext_vector_type(4))) short short4v;
typedef __attribute__((ext_vector_type(4))) float f32x4;

constexpr int Bb = 8, NN = 2048, FIN = 512, FOUT = 256;
#define LRALPHA 0.2f
#define MFMA16(a, b, c) __builtin_amdgcn_mfma_f32_16x16x32_bf16((a), (b), (c), 0, 0, 0)

static __device__ __forceinline__ ushort f2bf(float f) {
    unsigned u = __float_as_uint(f);
    u += 0x7fffu + ((u >> 16) & 1u);
    return (ushort)(u >> 16);
}
static __device__ __forceinline__ float bf2f(ushort b) { return __uint_as_float(((unsigned)b) << 16); }

// LDS-only barrier: waits ds ops (write visibility) but leaves global loads
// (vmcnt) in flight across the barrier — unlike __syncthreads().
#define LDSBAR() do { asm volatile("s_waitcnt lgkmcnt(0)" ::: "memory"); \
                      __builtin_amdgcn_s_barrier(); \
                      asm volatile("" ::: "memory"); } while (0)
#define BARONLY() do { asm volatile("" ::: "memory"); \
                       __builtin_amdgcn_s_barrier(); \
                       asm volatile("" ::: "memory"); } while (0)

// ---------------------------------------------------------------------------
// K0: prep. Block k (512): read W row k (coalesced), write WTh/WTl [n][k]
// (bf16 hi/lo split), and reduce wa1[k] = W[k,:]·a1, wa2[k] = W[k,:]·a2.
// ---------------------------------------------------------------------------
__global__ __launch_bounds__(256) void prep(const float* __restrict__ W,
                                            const float* __restrict__ a,
                                            ushort* __restrict__ WTh,
                                            ushort* __restrict__ WTl,
                                            float* __restrict__ wa1,
                                            float* __restrict__ wa2) {
    __shared__ float r1[4], r2[4];
    const int k = blockIdx.x, n = threadIdx.x;
    const int lane = n & 63, wv = n >> 6;
    const float w = W[(size_t)k * FOUT + n];
    const ushort hi = f2bf(w);
    WTh[(size_t)n * FIN + k] = hi;
    WTl[(size_t)n * FIN + k] = f2bf(w - bf2f(hi));
    float p1 = w * a[n], p2 = w * a[FOUT + n];
#pragma unroll
    for (int m = 1; m < 64; m <<= 1) {
        p1 += __shfl_xor(p1, m);
        p2 += __shfl_xor(p2, m);
    }
    if (lane == 0) { r1[wv] = p1; r2[wv] = p2; }
    __syncthreads();
    if (n == 0) {
        wa1[k] = r1[0] + r1[1] + r1[2] + r1[3];
        wa2[k] = r2[0] + r2[1] + r2[2] + r2[3];
    }
}

// ---------------------------------------------------------------------------
// K1: h = x @ W (split: xh*(Wh+Wl)) + fused s/t dots (x@wa1, x@wa2, exact
// fp32) + transposed bf16 hT write. 64m x 128n, BK=64, 512 thr / 8 waves.
// Raw barriers (no vmcnt drain); x depth-2 rotation, B depth-1 ping-pong.
// ---------------------------------------------------------------------------
__global__ __launch_bounds__(512, 4) void gemm_h(const float* __restrict__ x,
                                                 const ushort* __restrict__ WTh,
                                                 const ushort* __restrict__ WTl,
                                                 const float* __restrict__ wa1,
                                                 const float* __restrict__ wa2,
                                                 ushort* __restrict__ hTh,
                                                 float* __restrict__ sv,
                                                 float* __restrict__ tv) {
    __shared__ ushort Ah[4][2][512];     // 8 KB A frags
    __shared__ float SR1[64][8];         // 2 KB s partials
    __shared__ float SR2[64][8];         // 2 KB t partials
    __shared__ ushort Tr[8][16][72];     // 18.4 KB transpose buffer

    const int t = threadIdx.x, lane = t & 63, w = t >> 6;
    const int m0 = (blockIdx.x >> 1) * 64;
    const int n0 = (blockIdx.x & 1) * 128;

    const int ql = t & 63, qks = (t >> 6) & 1, qif = t >> 7;
    const int kcol = qks * 32 + (ql >> 4) * 8;
    const int arow = qif * 16 + (ql & 15);
    const float* xp = x + (size_t)(m0 + arow) * FIN + kcol;

    const size_t boff = (size_t)(n0 + w * 16 + (lane & 15)) * FIN + (lane >> 4) * 8;
    const ushort* bph = WTh + boff;
    const ushort* bpl = WTl + boff;

    f32x4 acc[4];
#pragma unroll
    for (int f = 0; f < 4; ++f) acc[f] = (f32x4){0.f, 0.f, 0.f, 0.f};
    float sp = 0.f, tp = 0.f;

    // prologue: x(0), x(1), B(0)
    float4 xa0 = *(const float4*)(xp + 0),  xa1 = *(const float4*)(xp + 4);
    float4 xb0 = *(const float4*)(xp + 64), xb1 = *(const float4*)(xp + 68);
    float4 xc0, xc1, xd0, xd1;
    short8 bhA0 = *(const short8*)(bph + 0),  blA0 = *(const short8*)(bpl + 0);
    short8 bhA1 = *(const short8*)(bph + 32), blA1 = *(const short8*)(bpl + 32);
    short8 bhB0, blB0, bhB1, blB1;

    auto phase = [&](int kt, const float4& c0, const float4& c1, float4& n0_, float4& n1_,
                     const short8& cbh0, const short8& cbl0, const short8& cbh1, const short8& cbl1,
                     short8& nbh0, short8& nbl0, short8& nbh1, short8& nbl1) {
        const int k0 = kt * 64;
        const float fv[8] = {c0.x, c0.y, c0.z, c0.w, c1.x, c1.y, c1.z, c1.w};
        short8 vh;
#pragma unroll
        for (int e = 0; e < 8; ++e) vh[e] = (short)f2bf(fv[e]);
        // s/t partials (exact fp32, x @ wa)
        const float4 w1a = *(const float4*)(wa1 + k0 + kcol);
        const float4 w1b = *(const float4*)(wa1 + k0 + kcol + 4);
        const float4 w2a = *(const float4*)(wa2 + k0 + kcol);
        const float4 w2b = *(const float4*)(wa2 + k0 + kcol + 4);
        sp += fv[0]*w1a.x + fv[1]*w1a.y + fv[2]*w1a.z + fv[3]*w1a.w
            + fv[4]*w1b.x + fv[5]*w1b.y + fv[6]*w1b.z + fv[7]*w1b.w;
        tp += fv[0]*w2a.x + fv[1]*w2a.y + fv[2]*w2a.z + fv[3]*w2a.w
            + fv[4]*w2b.x + fv[5]*w2b.y + fv[6]*w2b.z + fv[7]*w2b.w;
        BARONLY();                              // WAR: prev A reads done
        *(short8*)&Ah[qif][qks][ql * 8] = vh;
        LDSBAR();                               // A(kt) visible, vmcnt untouched
        // prefetch x(kt+2), B(kt+1)
        const int kx = (kt + 2 < 8 ? kt + 2 : 7) * 64;
        n0_ = *(const float4*)(xp + kx);
        n1_ = *(const float4*)(xp + kx + 4);
        const int kb = (kt + 1 < 8 ? kt + 1 : 7) * 64;
        nbh0 = *(const short8*)(bph + kb);
        nbl0 = *(const short8*)(bpl + kb);
        nbh1 = *(const short8*)(bph + kb + 32);
        nbl1 = *(const short8*)(bpl + kb + 32);
#pragma unroll
        for (int f = 0; f < 4; ++f) {
            const short8 a0 = *(const short8*)&Ah[f][0][lane * 8];
            const short8 a1 = *(const short8*)&Ah[f][1][lane * 8];
            acc[f] = MFMA16(a0, cbh0, acc[f]);
            acc[f] = MFMA16(a0, cbl0, acc[f]);
            acc[f] = MFMA16(a1, cbh1, acc[f]);
            acc[f] = MFMA16(a1, cbl1, acc[f]);
        }
    };

    for (int kt = 0; kt < 8; kt += 4) {
        phase(kt + 0, xa0, xa1, xc0, xc1, bhA0, blA0, bhA1, blA1, bhB0, blB0, bhB1, blB1);
        phase(kt + 1, xb0, xb1, xd0, xd1, bhB0, blB0, bhB1, blB1, bhA0, blA0, bhA1, blA1);
        phase(kt + 2, xc0, xc1, xa0, xa1, bhA0, blA0, bhA1, blA1, bhB0, blB0, bhB1, blB1);
        phase(kt + 3, xd0, xd1, xb0, xb1, bhB0, blB0, bhB1, blB1, bhA0, blA0, bhA1, blA1);
    }

    // ---- epilogue: s/t reduce (8 partials per row) ----
    SR1[arow][qks * 4 + (ql >> 4)] = sp;
    SR2[arow][qks * 4 + (ql >> 4)] = tp;

    // ---- epilogue: transposed bf16 write via LDS ----
    const int rb = (lane >> 4) * 4;
#pragma unroll
    for (int f = 0; f < 4; ++f)
#pragma unroll
        for (int r = 0; r < 4; ++r)
            Tr[w][lane & 15][f * 16 + rb + r] = f2bf(acc[f][r]);
    __syncthreads();
    if (t < 64 && n0 == 0) {
        float s = 0.f, tt2 = 0.f;
#pragma unroll
        for (int q = 0; q < 8; ++q) { s += SR1[t][q]; tt2 += SR2[t][q]; }
        sv[m0 + t] = s;
        tv[m0 + t] = tt2;
    }
    const int c = lane >> 2, rowb = (lane & 3) * 16;
    const ushort* src = &Tr[w][c][rowb];
    const short8 v0 = *(const short8*)src;
    const short8 v1 = *(const short8*)(src + 8);
    ushort* dst = hTh + ((size_t)(m0 >> 11) * FOUT + n0 + w * 16 + c) * NN + (m0 & 2047) + rowb;
    *(short8*)dst = v0;
    *(short8*)(dst + 8) = v1;
}

// ---------------------------------------------------------------------------
// K2: fused masked softmax + P@H (MFMA) + elu.
// 32 i-rows/block, b = blockIdx&7 (XCD L2 affinity). 512 thr / 8 waves.
// Raw LDS barriers (global prefetches never drained); adj depth-2 period-4
// register rotation; H depth-1 ping-pong; P dbuf in LDS, 1 barrier/phase.
// ---------------------------------------------------------------------------
__global__ __launch_bounds__(512, 4) void gat_fused(const int* __restrict__ adj,
                                                    const ushort* __restrict__ hTh,
                                                    const float* __restrict__ sv,
                                                    const float* __restrict__ tv,
                                                    float* __restrict__ out) {
    __shared__ float t_l[NN];             // 8 KB
    __shared__ ushort Pf[2][2][2][512];   // 8 KB [buf][ifrag][kstep][lane*8]
    __shared__ float den_sl[32][17];
    __shared__ float den_l[32];

    const int t = threadIdx.x, lane = t & 63, w = t >> 6;
    const int b = blockIdx.x & 7, i0 = (blockIdx.x >> 3) * 32;

    *(float4*)&t_l[t * 4] = *(const float4*)&tv[b * NN + t * 4];

    // P-writer mapping
    const int pf_ = t >> 8, pks = (t >> 7) & 1, pl = (t >> 1) & 63, ph = t & 1;
    const int prow = (pf_ << 4) | (pl & 15);
    const int pj = (pks << 5) | ((pl >> 4) << 3) | (ph << 2);
    const int slot = ph | ((pl >> 4) << 1) | (pks << 3);
    const float s_i = sv[b * NN + i0 + prow];
    const int* adjp = adj + ((size_t)b * NN + i0 + prow) * NN + pj;
    ushort* pdst0 = &Pf[0][pf_][pks][pl * 8 + ph * 4];
    ushort* pdst1 = &Pf[1][pf_][pks][pl * 8 + ph * 4];

    // H fragment base addresses (wave w owns cfrags 2w, 2w+1)
    const ushort* hb = hTh + (size_t)b * FOUT * NN;
    const ushort* h00 = hb + (size_t)(2 * w * 16 + (lane & 15)) * NN + (lane >> 4) * 8;
    const ushort* h10 = hb + (size_t)((2 * w + 1) * 16 + (lane & 15)) * NN + (lane >> 4) * 8;

    f32x4 acc00 = {0.f,0.f,0.f,0.f}, acc01 = acc00, acc10 = acc00, acc11 = acc00;
    float den_part = 0.f;

    // prologue: adj tiles 0,1; H tile 0
    int4 ajA = *(const int4*)(adjp);
    int4 ajB = *(const int4*)(adjp + 64);
    int4 ajC, ajD;
    short8 X00 = *(const short8*)h00, X01 = *(const short8*)(h00 + 32);
    short8 X10 = *(const short8*)h10, X11 = *(const short8*)(h10 + 32);
    short8 Y00, Y01, Y10, Y11;

    __syncthreads();   // t_l ready (once; drains prologue loads, fine)

    auto phase = [&](int jt, ushort* pdst, int rbuf,
                     const int4& ajcur, int4& aj2,
                     const short8& c00, const short8& c01, const short8& c10, const short8& c11,
                     short8& n00, short8& n01, short8& n10, short8& n11) {
        const int j0 = jt * 64;
        const int jH = min(j0 + 64, NN - 64);    // H prefetch t+1
        const int jA = min(j0 + 128, NN - 64);   // adj prefetch t+2
        n00 = *(const short8*)(h00 + jH);
        n01 = *(const short8*)(h00 + jH + 32);
        n10 = *(const short8*)(h10 + jH);
        n11 = *(const short8*)(h10 + jH + 32);
        aj2 = *(const int4*)(adjp + jA);
        const float4 tq = *(const float4*)&t_l[j0 + pj];
        const float tvv[4] = {tq.x, tq.y, tq.z, tq.w};
        const int avs[4] = {ajcur.x, ajcur.y, ajcur.z, ajcur.w};
        short4v pv;
#pragma unroll
        for (int e = 0; e < 4; ++e) {
            float v = s_i + tvv[e];
            v = v > 0.f ? v : LRALPHA * v;
            const float wv = avs[e] > 0 ? __expf(v) : 0.f;
            const ushort hbv = f2bf(wv);
            den_part += bf2f(hbv);
            pv[e] = (short)hbv;
        }
        *(short4v*)pdst = pv;
        LDSBAR();   // P(t) visible; in-flight global prefetches NOT drained
        const ushort* pr = &Pf[rbuf][0][0][0] + lane * 8;
        const short8 a00 = *(const short8*)(pr);
        const short8 a01 = *(const short8*)(pr + 512);
        const short8 a10 = *(const short8*)(pr + 1024);
        const short8 a11 = *(const short8*)(pr + 1536);
        __builtin_amdgcn_s_setprio(1);
        acc00 = MFMA16(a00, c00, acc00);
        acc00 = MFMA16(a01, c01, acc00);
        acc01 = MFMA16(a00, c10, acc01);
        acc01 = MFMA16(a01, c11, acc01);
        acc10 = MFMA16(a10, c00, acc10);
        acc10 = MFMA16(a11, c01, acc10);
        acc11 = MFMA16(a10, c10, acc11);
        acc11 = MFMA16(a11, c11, acc11);
        __builtin_amdgcn_s_setprio(0);
    };

    for (int tt = 0; tt < NN / 64; tt += 4) {
        phase(tt + 0, pdst0, 0, ajA, ajC, X00, X01, X10, X11, Y00, Y01, Y10, Y11);
        phase(tt + 1, pdst1, 1, ajB, ajD, Y00, Y01, Y10, Y11, X00, X01, X10, X11);
        phase(tt + 2, pdst0, 0, ajC, ajA, X00, X01, X10, X11, Y00, Y01, Y10, Y11);
        phase(tt + 3, pdst1, 1, ajD, ajB, Y00, Y01, Y10, Y11, X00, X01, X10, X11);
    }

    // ---- denominator reduction ----
    den_sl[prow][slot] = den_part;
    __syncthreads();
    if (t < 32) {
        float s = 0.f;
#pragma unroll
        for (int k = 0; k < 16; ++k) s += den_sl[t][k];
        den_l[t] = s;
    }
    __syncthreads();

    // ---- epilogue: normalize + elu + store ----
    const int rb = (lane >> 4) * 4;
    const f32x4 av[2][2] = {{acc00, acc01}, {acc10, acc11}};
#pragma unroll
    for (int f = 0; f < 2; ++f) {
#pragma unroll
        for (int r = 0; r < 4; ++r) {
            const int row = f * 16 + rb + r;
            const float inv = 1.0f / den_l[row];
#pragma unroll
            for (int cf = 0; cf < 2; ++cf) {
                float v = av[f][cf][r] * inv;
                v = v > 0.f ? v : expm1f(v);
                out[((size_t)b * NN + i0 + row) * FOUT + w * 32 + cf * 16 + (lane & 15)] = v;
            }
        }
    }
}

// ---------------------------------------------------------------------------
extern "C" void kernel_launch(void* const* d_in, const int* in_sizes, int n_in,
                              void* d_out, int out_size, void* d_ws, size_t ws_size,
                              hipStream_t stream) {
    const float* x   = (const float*)d_in[0];
    const int*   adj = (const int*)d_in[1];
    const float* W   = (const float*)d_in[2];
    const float* a   = (const float*)d_in[3];
    float* out = (float*)d_out;

    // ws: hTh 8MB | sv 64KB | tv 64KB | WTh 0.5MB | WTl 0.5MB | wa1 2KB | wa2 2KB
    ushort* hTh = (ushort*)d_ws;
    float*  sv  = (float*)(hTh + (size_t)Bb * FOUT * NN);
    float*  tv  = sv + Bb * NN;
    ushort* WTh = (ushort*)(tv + Bb * NN);
    ushort* WTl = WTh + (size_t)FIN * FOUT;
    float*  wa1 = (float*)(WTl + (size_t)FIN * FOUT);
    float*  wa2 = wa1 + FIN;

    prep<<<FIN, 256, 0, stream>>>(W, a, WTh, WTl, wa1, wa2);
    gemm_h<<<512, 512, 0, stream>>>(x, WTh, WTl, wa1, wa2, hTh, sv, tv);
    gat_fused<<<512, 512, 0, stream>>>(adj, hTh, sv, tv, out);
}